// Round 2
// baseline (335.563 us; speedup 1.0000x reference)
//
#include <hip/hip_runtime.h>
#include <stdint.h>

// SuperpointGenerator v11: eliminate the duplicated recount. v10's K4
// (bucket_hist) and K6 (collect2) both re-read lists (33.6 MB) and rebuilt
// the 16 KB per-bucket cnt[] via 8.4M LDS byte-atomics. Now K4 compacts
// cnt[] nonzeros into an id-ordered pair stream (id<<8 | count, ~13 MB)
// via a block-wide exclusive scan; K6 is a light pair scan (no LDS
// recount, no lists re-read). Tier id-ordering preserved: pairs are
// ascending-id within bucket, buckets ordered by tbase (bhist-derived).
// Pipeline:
//   K1 vidx_count   : coords -> vidx + per-(block,bucket) counts
//   K2 scan64       : per-batch prefix -> blkbase/bukbase/buktot (+paircur=0)
//   K3 scatter4     : vidx -> bucket-segmented lists (LDS counting sort)
//   K4 bucket_hist  : per-bucket LDS count -> 256-bin hist + (id,cnt) pairs
//   K5 select_params: T, A=#{c>T}, m, per-bucket winner/tier bases
//   K6 collect2     : pair scan -> winners (c>T) + id-ordered tier (c==T)
//   K7 rank512      : rank by (count desc, id asc) -> packed lookup
//   K8 write_labels4: binary-search packed table, int4 in/out

#define BATCHES 32
#define NPTS    (1 << 18)
#define MAX_SP  512
#define NBUK    76
#define BUK_VOX 16384
#define DRANGE  (NBUK * BUK_VOX)     // 1245184
#define OFFSET  (DRANGE / 2)         // 622592
#define BUK_DW  (BUK_VOX / 4)        // 4096
#define TIERCAP 18432
#define BPB     64                   // blocks per batch in K1/K3/K8
#define PPB     (NPTS / BPB)         // 4096 points per block

typedef float    f32x4 __attribute__((ext_vector_type(4)));
typedef int      i32x4 __attribute__((ext_vector_type(4)));
typedef uint32_t u32x4 __attribute__((ext_vector_type(4)));

__device__ __forceinline__ int pidx(float x, float y, float z) {
    int vx = (int)(x / 0.2f);        // IEEE f32 divide + trunc-to-zero == ref
    int vy = (int)(y / 0.2f);
    int vz = (int)(z / 0.2f);
    int id = vx * 10000 + vy * 100 + vz;
    int idx = id + OFFSET;
    idx = idx < 0 ? 0 : (idx >= DRANGE ? DRANGE - 1 : idx);  // memory safety only
    return idx;
}

// ---- K1: vidx (4 pts/thread, float4 loads) + per-(block,bucket) counts ----
__global__ void __launch_bounds__(1024) vidx_count(
    const float* __restrict__ coords, int* __restrict__ vidx,
    int* __restrict__ blkcnt)
{
    int b = blockIdx.x >> 6, blk = blockIdx.x & 63, tid = threadIdx.x;
    __shared__ int cnt[NBUK];
    if (tid < NBUK) cnt[tid] = 0;
    __syncthreads();
    size_t p0 = (size_t)b * NPTS + (size_t)blk * PPB + (size_t)tid * 4;
    const f32x4* cp = (const f32x4*)(coords + p0 * 3);   // 48 B, 16B-aligned
    f32x4 a = __builtin_nontemporal_load(cp + 0);
    f32x4 c = __builtin_nontemporal_load(cp + 1);
    f32x4 d = __builtin_nontemporal_load(cp + 2);
    i32x4 iv;
    iv[0] = pidx(a[0], a[1], a[2]);
    iv[1] = pidx(a[3], c[0], c[1]);
    iv[2] = pidx(c[2], c[3], d[0]);
    iv[3] = pidx(d[1], d[2], d[3]);
    __builtin_nontemporal_store(iv, (i32x4*)(vidx + p0));
    atomicAdd(&cnt[iv[0] >> 14], 1);
    atomicAdd(&cnt[iv[1] >> 14], 1);
    atomicAdd(&cnt[iv[2] >> 14], 1);
    atomicAdd(&cnt[iv[3] >> 14], 1);
    __syncthreads();
    if (tid < NBUK) blkcnt[blockIdx.x * NBUK + tid] = cnt[tid];
}

// ---- K2: per-batch scan over 64 blocks -> bases (+ zero pair cursor) ----
__global__ void __launch_bounds__(128) scan64(
    const int* __restrict__ blkcnt, int* __restrict__ blkbase,
    int* __restrict__ bukbase, int* __restrict__ buktot,
    int* __restrict__ paircur)
{
    int b = blockIdx.x, tid = threadIdx.x;
    __shared__ int c[BPB * NBUK];    // 19456 B
    __shared__ int start[NBUK];
    if (tid == 0) paircur[b] = 0;
    for (int i = tid; i < BPB * NBUK; i += 128)
        c[i] = blkcnt[(size_t)b * BPB * NBUK + i];
    __syncthreads();
    if (tid < NBUK) {
        int s = 0;
        for (int blk = 0; blk < BPB; ++blk) s += c[blk * NBUK + tid];
        buktot[b * NBUK + tid] = s;
        start[tid] = s;
    }
    __syncthreads();
    if (tid == 0) {
        int run = 0;
        for (int k = 0; k < NBUK; ++k) { int t = start[k]; start[k] = run; run += t; }
    }
    __syncthreads();
    if (tid < NBUK) {
        int run = start[tid];
        bukbase[b * NBUK + tid] = run;
        for (int blk = 0; blk < BPB; ++blk) {
            blkbase[((size_t)b * BPB + blk) * NBUK + tid] = run;
            run += c[blk * NBUK + tid];
        }
    }
}

// ---- K3: LDS counting-sort scatter -> coalesced segment writes ----
__global__ void __launch_bounds__(1024) scatter4(
    const int* __restrict__ vidx, const int* __restrict__ blkcnt,
    const int* __restrict__ blkbase, int* __restrict__ lists)
{
    int b = blockIdx.x >> 6, tid = threadIdx.x;
    __shared__ int stage[PPB];       // 16 KB: points sorted by bucket
    __shared__ int offs[NBUK];       // within-block exclusive prefix
    __shared__ int cur[NBUK];        // LDS cursors
    __shared__ int rebase[NBUK];     // blkbase[k] - offs[k]
    if (tid < NBUK) offs[tid] = blkcnt[blockIdx.x * NBUK + tid];
    __syncthreads();
    if (tid == 0) {
        int run = 0;
        for (int k = 0; k < NBUK; ++k) { int t = offs[k]; offs[k] = run; run += t; }
    }
    __syncthreads();
    if (tid < NBUK) {
        cur[tid] = offs[tid];
        rebase[tid] = blkbase[blockIdx.x * NBUK + tid] - offs[tid];
    }
    __syncthreads();
    size_t p0 = (size_t)b * NPTS + (size_t)(blockIdx.x & 63) * PPB + (size_t)tid * 4;
    i32x4 iv = __builtin_nontemporal_load((const i32x4*)(vidx + p0));
    #pragma unroll
    for (int j = 0; j < 4; ++j) {
        int idx = iv[j];
        stage[atomicAdd(&cur[idx >> 14], 1)] = idx;
    }
    __syncthreads();
    int* lb = lists + (size_t)b * NPTS;
    #pragma unroll
    for (int j = 0; j < 4; ++j) {
        int i = j * 1024 + tid;      // lane-consecutive -> coalesced runs
        int v = stage[i];
        __builtin_nontemporal_store(v, &lb[rebase[v >> 14] + i]);
    }
}

// ---- K4: per-(batch,bucket) LDS count -> 256-bin hist + compact pairs ----
__global__ void __launch_bounds__(1024) bucket_hist(
    const int* __restrict__ lists, const int* __restrict__ bukbase,
    const int* __restrict__ buktot, int* __restrict__ bhist,
    uint32_t* __restrict__ pairs, int* __restrict__ paircur,
    int* __restrict__ pairbase, int* __restrict__ pairn)
{
    int k = blockIdx.x, b = blockIdx.y, tid = threadIdx.x;
    __shared__ uint32_t cnt[BUK_DW];     // 16 KB
    __shared__ uint32_t h8[8 * 256];     // 8 KB
    __shared__ int woff[16];             // per-wave pair totals
    __shared__ int sbase;
    for (int i = tid; i < BUK_DW; i += 1024) cnt[i] = 0;
    for (int i = tid; i < 8 * 256; i += 1024) h8[i] = 0;
    __syncthreads();
    int st = bukbase[b * NBUK + k], n = buktot[b * NBUK + k];
    const int* seg = lists + (size_t)b * NPTS + st;
    for (int i = tid; i < n; i += 1024) {
        int idx = seg[i] & (BUK_VOX - 1);
        atomicAdd(&cnt[idx >> 2], 1u << ((idx & 3) * 8));
    }
    __syncthreads();
    // pass 2: thread t owns dwords [4t, 4t+4) = ids [16t, 16t+16), contiguous
    // -> id-ascending within thread, tid-ascending -> pair stream id-ordered.
    u32x4 w4 = ((const u32x4*)cnt)[tid];
    int rep = (tid >> 7) & 7;
    int nz = 0;
    #pragma unroll
    for (int d = 0; d < 4; ++d) {
        uint32_t w = w4[d];
        if (!w) continue;
        #pragma unroll
        for (int j = 0; j < 4; ++j) {
            uint32_t cc = (w >> (j * 8)) & 255u;
            if (cc) { ++nz; atomicAdd(&h8[rep * 256 + cc], 1u); }
        }
    }
    // block-wide exclusive scan of nz (wave shfl + 16-wave LDS pass)
    int lane = tid & 63, wv = tid >> 6;
    int inc = nz;
    #pragma unroll
    for (int s = 1; s < 64; s <<= 1) {
        int y = __shfl_up(inc, s);
        if (lane >= s) inc += y;
    }
    int pre = inc - nz;
    if (lane == 63) woff[wv] = inc;
    __syncthreads();
    if (tid == 0) {
        int run = 0;
        for (int i = 0; i < 16; ++i) { int t = woff[i]; woff[i] = run; run += t; }
        sbase = atomicAdd(&paircur[b], run);
        pairbase[b * NBUK + k] = sbase;
        pairn[b * NBUK + k] = run;
    }
    __syncthreads();
    int off = sbase + woff[wv] + pre;
    uint32_t* pp = pairs + (size_t)b * NPTS;
    int base_id = k * BUK_VOX + tid * 16;
    #pragma unroll
    for (int d = 0; d < 4; ++d) {
        uint32_t w = w4[d];
        if (!w) continue;
        #pragma unroll
        for (int j = 0; j < 4; ++j) {
            uint32_t cc = (w >> (j * 8)) & 255u;
            if (cc) pp[off++] = ((uint32_t)(base_id + d * 4 + j) << 8) | cc;
        }
    }
    __syncthreads();
    if (tid < 256) {
        uint32_t s = 0;
        #pragma unroll
        for (int r = 0; r < 8; ++r) s += h8[r * 256 + tid];
        bhist[((size_t)b * NBUK + k) * 256 + tid] = (int)s;
    }
}

// ---- K5: derive T/A/m/nu and per-bucket winner/tier exclusive bases ----
__global__ void __launch_bounds__(256) select_params(
    const int* __restrict__ bhist, int* __restrict__ params,
    int* __restrict__ wbase, int* __restrict__ tbase)
{
    int b = blockIdx.x, tid = threadIdx.x;
    __shared__ int tot[256];
    __shared__ int wc_[NBUK], tc_[NBUK];
    __shared__ int sh_T;
    int s = 0;
    for (int k = 0; k < NBUK; ++k) s += bhist[((size_t)b * NBUK + k) * 256 + tid];
    tot[tid] = s;
    __syncthreads();
    if (tid == 0) {
        int nu = 0;
        for (int c = 1; c < 256; ++c) nu += tot[c];
        int acc = 0, c = 255;
        while (c > 1 && acc + tot[c] < MAX_SP) { acc += tot[c]; --c; }
        int T = c, A = acc;
        int m = MAX_SP - A; if (m > tot[T]) m = tot[T];   // nu<=512: whole tier
        params[b * 8 + 0] = T;  params[b * 8 + 1] = A;
        params[b * 8 + 2] = m;  params[b * 8 + 3] = nu;
        params[b * 8 + 4] = A + m;                        // nw = min(512, nu)
        sh_T = T;
    }
    __syncthreads();
    int T = sh_T;
    if (tid < NBUK) {
        int ws = 0;
        const int* bh = bhist + ((size_t)b * NBUK + tid) * 256;
        for (int c = T + 1; c < 256; ++c) ws += bh[c];
        wc_[tid] = ws;
        tc_[tid] = bh[T];
    }
    __syncthreads();
    if (tid == 0) {
        int aw = 0, at = 0;
        for (int k = 0; k < NBUK; ++k) {
            wbase[b * NBUK + k] = aw; tbase[b * NBUK + k] = at;
            aw += wc_[k]; at += tc_[k];
        }
    }
}

// ---- K6: pair scan -> winners (any order) + tier (exact id order) ----
__global__ void __launch_bounds__(512) collect2(
    const uint32_t* __restrict__ pairs, const int* __restrict__ pairbase,
    const int* __restrict__ pairn, const int* __restrict__ params,
    const int* __restrict__ wbase, const int* __restrict__ tbase,
    uint32_t* __restrict__ wid, int* __restrict__ wcnt, uint32_t* __restrict__ tier)
{
    int k = blockIdx.x, b = blockIdx.y, tid = threadIdx.x;
    int T = params[b * 8 + 0], m = params[b * 8 + 2];
    int wb = wbase[b * NBUK + k], tb = tbase[b * NBUK + k];
    int pb = pairbase[b * NBUK + k], P = pairn[b * NBUK + k];
    const uint32_t* pp = pairs + (size_t)b * NPTS + pb;
    __shared__ int tl[512];
    __shared__ int wpos;
    if (tid == 0) wpos = 0;
    __syncthreads();
    // ordered chunks: thread t owns pairs [t*C, (t+1)*C) -> id order preserved
    int C = (P + 511) >> 9;
    int s0 = tid * C, s1 = s0 + C; if (s1 > P) s1 = P;
    int ntier = 0;
    for (int i = s0; i < s1; ++i) {
        uint32_t pr = pp[i];
        int c = (int)(pr & 255u);
        if (c > T) {
            int p = atomicAdd(&wpos, 1);
            wid [b * MAX_SP + wb + p] = pr >> 8;
            wcnt[b * MAX_SP + wb + p] = c;
        } else if (c == T) ++ntier;
    }
    tl[tid] = ntier;
    __syncthreads();
    if (tb < m && ntier > 0) {           // only blocks that can hold tier[0..m)
        int pre = 0;
        for (int j = 0; j < 512; ++j) { int t = tl[j]; if (j < tid) pre += t; }
        int pos = tb + pre, kk = 0;
        for (int i = s0; i < s1; ++i) {
            uint32_t pr = pp[i];
            if ((int)(pr & 255u) == T) {
                int q2 = pos + kk; ++kk;
                if (q2 < TIERCAP) tier[b * TIERCAP + q2] = pr >> 8;
            }
        }
    }
}

// ---- K7: rank 512 winners; emit PACKED table (idx<<9 | label), sorted by idx ----
__global__ void __launch_bounds__(512) rank512(
    const int* __restrict__ params, const uint32_t* __restrict__ wid,
    const int* __restrict__ wcnt, const uint32_t* __restrict__ tier,
    uint32_t* __restrict__ lookup)
{
    int b = blockIdx.x, tid = threadIdx.x;
    int T = params[b * 8 + 0], A = params[b * 8 + 1];
    int nu = params[b * 8 + 3], nw = params[b * 8 + 4];
    __shared__ uint32_t wu[MAX_SP];
    __shared__ int      wc[MAX_SP];
    if (tid < A)       { wu[tid] = wid[b * MAX_SP + tid]; wc[tid] = wcnt[b * MAX_SP + tid]; }
    else if (tid < nw) { wu[tid] = tier[b * TIERCAP + (tid - A)]; wc[tid] = T; }
    __syncthreads();
    if (tid < nw) {
        uint32_t u = wu[tid]; int c = wc[tid];
        int r = 0, ur = 0;
        for (int j = 0; j < nw; ++j) {
            uint32_t uj = wu[j]; int cj = wc[j];
            r  += ((cj > c) || (cj == c && uj < u)) ? 1 : 0;
            ur += (uj < u) ? 1 : 0;
        }
        int label = (nu <= MAX_SP) ? ur : r;               // inverse branch: id-rank
        lookup[b * MAX_SP + ur] = (u << 9) | (uint32_t)label;   // idx 21b | label 9b
    }
}

// ---- K8: label 4 pts/thread via binary search of packed LDS table ----
__global__ void __launch_bounds__(1024) write_labels4(
    const int* __restrict__ vidx, const int* __restrict__ params,
    const uint32_t* __restrict__ lookup, int* __restrict__ out)
{
    __shared__ uint32_t lu[MAX_SP];
    int b = blockIdx.x >> 6, tid = threadIdx.x;
    if (tid < MAX_SP) lu[tid] = lookup[b * MAX_SP + tid];
    __syncthreads();
    int nw = params[b * 8 + 4];
    size_t p0 = (size_t)b * NPTS + (size_t)(blockIdx.x & 63) * PPB + (size_t)tid * 4;
    i32x4 iv = __builtin_nontemporal_load((const i32x4*)(vidx + p0));
    i32x4 ov;
    #pragma unroll
    for (int j = 0; j < 4; ++j) {
        uint32_t u = (uint32_t)iv[j];
        int lo = 0, hi = nw;
        while (lo < hi) { int mid = (lo + hi) >> 1; if ((lu[mid] >> 9) < u) lo = mid + 1; else hi = mid; }
        int label = 0;
        if (lo < nw && (lu[lo] >> 9) == u) label = (int)(lu[lo] & 511u);
        ov[j] = label;
    }
    __builtin_nontemporal_store(ov, (i32x4*)(out + p0));
}

extern "C" void kernel_launch(void* const* d_in, const int* in_sizes, int n_in,
                              void* d_out, int out_size, void* d_ws, size_t ws_size,
                              hipStream_t stream) {
    const float* coords = (const float*)d_in[0];
    int* out = (int*)d_out;

    uint8_t* p = (uint8_t*)d_ws;
    int*      vidx    = (int*)p;      p += (size_t)BATCHES * NPTS * 4;          // 33.6 MB
    int*      lists   = (int*)p;      p += (size_t)BATCHES * NPTS * 4;          // 33.6 MB
    uint32_t* pairs   = (uint32_t*)p; p += (size_t)BATCHES * NPTS * 4;          // 33.6 MB cap
    int*      blkcnt  = (int*)p;      p += (size_t)BATCHES * BPB * NBUK * 4;    // 623 KB
    int*      blkbase = (int*)p;      p += (size_t)BATCHES * BPB * NBUK * 4;    // 623 KB
    int*      bhist   = (int*)p;      p += (size_t)BATCHES * NBUK * 256 * 4;    // 2.5 MB
    uint32_t* tier    = (uint32_t*)p; p += (size_t)BATCHES * TIERCAP * 4;       // 2.4 MB
    int*      bukbase = (int*)p;      p += (size_t)BATCHES * NBUK * 4;
    int*      buktot  = (int*)p;      p += (size_t)BATCHES * NBUK * 4;
    int*      wbase   = (int*)p;      p += (size_t)BATCHES * NBUK * 4;
    int*      tbase   = (int*)p;      p += (size_t)BATCHES * NBUK * 4;
    int*      pairbase= (int*)p;      p += (size_t)BATCHES * NBUK * 4;
    int*      pairn   = (int*)p;      p += (size_t)BATCHES * NBUK * 4;
    int*      paircur = (int*)p;      p += (size_t)BATCHES * 4;
    int*      params  = (int*)p;      p += (size_t)BATCHES * 8 * 4;
    uint32_t* wid     = (uint32_t*)p; p += (size_t)BATCHES * MAX_SP * 4;
    int*      wcnt    = (int*)p;      p += (size_t)BATCHES * MAX_SP * 4;
    uint32_t* lookup  = (uint32_t*)p; p += (size_t)BATCHES * MAX_SP * 4;

    vidx_count   <<<BATCHES * BPB, 1024, 0, stream>>>(coords, vidx, blkcnt);
    scan64       <<<BATCHES, 128, 0, stream>>>(blkcnt, blkbase, bukbase, buktot, paircur);
    scatter4     <<<BATCHES * BPB, 1024, 0, stream>>>(vidx, blkcnt, blkbase, lists);
    bucket_hist  <<<dim3(NBUK, BATCHES), 1024, 0, stream>>>(lists, bukbase, buktot, bhist, pairs, paircur, pairbase, pairn);
    select_params<<<BATCHES, 256, 0, stream>>>(bhist, params, wbase, tbase);
    collect2     <<<dim3(NBUK, BATCHES), 512, 0, stream>>>(pairs, pairbase, pairn, params, wbase, tbase, wid, wcnt, tier);
    rank512      <<<BATCHES, 512, 0, stream>>>(params, wid, wcnt, tier, lookup);
    write_labels4<<<BATCHES * BPB, 1024, 0, stream>>>(vidx, params, lookup, out);
}

// Round 3
// 314.976 us; speedup vs baseline: 1.0654x; 1.0654x over previous
//
#include <hip/hip_runtime.h>
#include <stdint.h>

// SuperpointGenerator v12: v11's pair-stream handoff regressed (+8us: serial
// off++ scattered stores + extra scan/atomics in K4 outweighed K6 savings).
// Reverted. New handoff: K4 dumps its finished per-bucket cnt[] (16 KB, one
// coalesced dwordx4/thread it already has in registers) to global cnt16k
// (40 MB, L3-resident; workspace poison is a fixed 384 MiB fill so footprint
// is free). K6 loses LDS zeroing + lists re-read + 8.4M LDS atomics, becomes
// 2 coalesced dwordx4 loads + byte scan; serial 512-iter tl[] prefix replaced
// by shfl_up wave scan. Id-order invariants identical -> bit-exact output.
// Pipeline:
//   K1 vidx_count   : coords -> vidx + per-(block,bucket) counts
//   K2 scan64       : per-batch prefix -> blkbase/bukbase/buktot
//   K3 scatter4     : vidx -> bucket-segmented lists (LDS counting sort)
//   K4 bucket_hist  : per-bucket LDS count -> 256-bin hist + cnt16k dump
//   K5 select_params: T, A=#{c>T}, m, per-bucket winner/tier bases
//   K6 collect2     : cnt16k scan -> winners (c>T) + id-ordered tier (c==T)
//   K7 rank512      : rank by (count desc, id asc) -> packed lookup
//   K8 write_labels4: binary-search packed table, int4 in/out

#define BATCHES 32
#define NPTS    (1 << 18)
#define MAX_SP  512
#define NBUK    76
#define BUK_VOX 16384
#define DRANGE  (NBUK * BUK_VOX)     // 1245184
#define OFFSET  (DRANGE / 2)         // 622592
#define BUK_DW  (BUK_VOX / 4)        // 4096
#define TIERCAP 18432
#define BPB     64                   // blocks per batch in K1/K3/K8
#define PPB     (NPTS / BPB)         // 4096 points per block

typedef float    f32x4 __attribute__((ext_vector_type(4)));
typedef int      i32x4 __attribute__((ext_vector_type(4)));
typedef uint32_t u32x4 __attribute__((ext_vector_type(4)));

__device__ __forceinline__ int pidx(float x, float y, float z) {
    int vx = (int)(x / 0.2f);        // IEEE f32 divide + trunc-to-zero == ref
    int vy = (int)(y / 0.2f);
    int vz = (int)(z / 0.2f);
    int id = vx * 10000 + vy * 100 + vz;
    int idx = id + OFFSET;
    idx = idx < 0 ? 0 : (idx >= DRANGE ? DRANGE - 1 : idx);  // memory safety only
    return idx;
}

// ---- K1: vidx (4 pts/thread, float4 loads) + per-(block,bucket) counts ----
__global__ void __launch_bounds__(1024) vidx_count(
    const float* __restrict__ coords, int* __restrict__ vidx,
    int* __restrict__ blkcnt)
{
    int b = blockIdx.x >> 6, blk = blockIdx.x & 63, tid = threadIdx.x;
    __shared__ int cnt[NBUK];
    if (tid < NBUK) cnt[tid] = 0;
    __syncthreads();
    size_t p0 = (size_t)b * NPTS + (size_t)blk * PPB + (size_t)tid * 4;
    const f32x4* cp = (const f32x4*)(coords + p0 * 3);   // 48 B, 16B-aligned
    f32x4 a = __builtin_nontemporal_load(cp + 0);
    f32x4 c = __builtin_nontemporal_load(cp + 1);
    f32x4 d = __builtin_nontemporal_load(cp + 2);
    i32x4 iv;
    iv[0] = pidx(a[0], a[1], a[2]);
    iv[1] = pidx(a[3], c[0], c[1]);
    iv[2] = pidx(c[2], c[3], d[0]);
    iv[3] = pidx(d[1], d[2], d[3]);
    __builtin_nontemporal_store(iv, (i32x4*)(vidx + p0));
    atomicAdd(&cnt[iv[0] >> 14], 1);
    atomicAdd(&cnt[iv[1] >> 14], 1);
    atomicAdd(&cnt[iv[2] >> 14], 1);
    atomicAdd(&cnt[iv[3] >> 14], 1);
    __syncthreads();
    if (tid < NBUK) blkcnt[blockIdx.x * NBUK + tid] = cnt[tid];
}

// ---- K2: per-batch scan over 64 blocks -> bases ----
__global__ void __launch_bounds__(128) scan64(
    const int* __restrict__ blkcnt, int* __restrict__ blkbase,
    int* __restrict__ bukbase, int* __restrict__ buktot)
{
    int b = blockIdx.x, tid = threadIdx.x;
    __shared__ int c[BPB * NBUK];    // 19456 B
    __shared__ int start[NBUK];
    for (int i = tid; i < BPB * NBUK; i += 128)
        c[i] = blkcnt[(size_t)b * BPB * NBUK + i];
    __syncthreads();
    if (tid < NBUK) {
        int s = 0;
        for (int blk = 0; blk < BPB; ++blk) s += c[blk * NBUK + tid];
        buktot[b * NBUK + tid] = s;
        start[tid] = s;
    }
    __syncthreads();
    if (tid == 0) {
        int run = 0;
        for (int k = 0; k < NBUK; ++k) { int t = start[k]; start[k] = run; run += t; }
    }
    __syncthreads();
    if (tid < NBUK) {
        int run = start[tid];
        bukbase[b * NBUK + tid] = run;
        for (int blk = 0; blk < BPB; ++blk) {
            blkbase[((size_t)b * BPB + blk) * NBUK + tid] = run;
            run += c[blk * NBUK + tid];
        }
    }
}

// ---- K3: LDS counting-sort scatter -> coalesced segment writes ----
__global__ void __launch_bounds__(1024) scatter4(
    const int* __restrict__ vidx, const int* __restrict__ blkcnt,
    const int* __restrict__ blkbase, int* __restrict__ lists)
{
    int b = blockIdx.x >> 6, tid = threadIdx.x;
    __shared__ int stage[PPB];       // 16 KB: points sorted by bucket
    __shared__ int offs[NBUK];       // within-block exclusive prefix
    __shared__ int cur[NBUK];        // LDS cursors
    __shared__ int rebase[NBUK];     // blkbase[k] - offs[k]
    if (tid < NBUK) offs[tid] = blkcnt[blockIdx.x * NBUK + tid];
    __syncthreads();
    if (tid == 0) {
        int run = 0;
        for (int k = 0; k < NBUK; ++k) { int t = offs[k]; offs[k] = run; run += t; }
    }
    __syncthreads();
    if (tid < NBUK) {
        cur[tid] = offs[tid];
        rebase[tid] = blkbase[blockIdx.x * NBUK + tid] - offs[tid];
    }
    __syncthreads();
    size_t p0 = (size_t)b * NPTS + (size_t)(blockIdx.x & 63) * PPB + (size_t)tid * 4;
    i32x4 iv = __builtin_nontemporal_load((const i32x4*)(vidx + p0));
    #pragma unroll
    for (int j = 0; j < 4; ++j) {
        int idx = iv[j];
        stage[atomicAdd(&cur[idx >> 14], 1)] = idx;
    }
    __syncthreads();
    int* lb = lists + (size_t)b * NPTS;
    #pragma unroll
    for (int j = 0; j < 4; ++j) {
        int i = j * 1024 + tid;      // lane-consecutive -> coalesced runs
        int v = stage[i];
        __builtin_nontemporal_store(v, &lb[rebase[v >> 14] + i]);
    }
}

// ---- K4: per-(batch,bucket) LDS count -> 256-bin hist + cnt16k dump ----
__global__ void __launch_bounds__(1024) bucket_hist(
    const int* __restrict__ lists, const int* __restrict__ bukbase,
    const int* __restrict__ buktot, int* __restrict__ bhist,
    uint32_t* __restrict__ cnt16k)
{
    int k = blockIdx.x, b = blockIdx.y, tid = threadIdx.x;
    __shared__ uint32_t cnt[BUK_DW];     // 16 KB
    __shared__ uint32_t h8[8 * 256];     // 8 KB
    for (int i = tid; i < BUK_DW; i += 1024) cnt[i] = 0;
    for (int i = tid; i < 8 * 256; i += 1024) h8[i] = 0;
    __syncthreads();
    int st = bukbase[b * NBUK + k], n = buktot[b * NBUK + k];
    const int* seg = lists + (size_t)b * NPTS + st;
    for (int i = tid; i < n; i += 1024) {
        int idx = seg[i] & (BUK_VOX - 1);
        atomicAdd(&cnt[idx >> 2], 1u << ((idx & 3) * 8));
    }
    __syncthreads();
    // thread t owns dwords [4t,4t+4): hist update + coalesced dump (regular
    // store -> stays L2/L3 resident for K6)
    u32x4 w4 = ((const u32x4*)cnt)[tid];
    ((u32x4*)(cnt16k + (size_t)(b * NBUK + k) * BUK_DW))[tid] = w4;
    int rep = (tid >> 7) & 7;
    #pragma unroll
    for (int d = 0; d < 4; ++d) {
        uint32_t w = w4[d];
        if (!w) continue;
        #pragma unroll
        for (int j = 0; j < 4; ++j) {
            uint32_t cc = (w >> (j * 8)) & 255u;
            if (cc) atomicAdd(&h8[rep * 256 + cc], 1u);
        }
    }
    __syncthreads();
    if (tid < 256) {
        uint32_t s = 0;
        #pragma unroll
        for (int r = 0; r < 8; ++r) s += h8[r * 256 + tid];
        bhist[((size_t)b * NBUK + k) * 256 + tid] = (int)s;
    }
}

// ---- K5: derive T/A/m/nu and per-bucket winner/tier exclusive bases ----
__global__ void __launch_bounds__(256) select_params(
    const int* __restrict__ bhist, int* __restrict__ params,
    int* __restrict__ wbase, int* __restrict__ tbase)
{
    int b = blockIdx.x, tid = threadIdx.x;
    __shared__ int tot[256];
    __shared__ int wc_[NBUK], tc_[NBUK];
    __shared__ int sh_T;
    int s = 0;
    for (int k = 0; k < NBUK; ++k) s += bhist[((size_t)b * NBUK + k) * 256 + tid];
    tot[tid] = s;
    __syncthreads();
    if (tid == 0) {
        int nu = 0;
        for (int c = 1; c < 256; ++c) nu += tot[c];
        int acc = 0, c = 255;
        while (c > 1 && acc + tot[c] < MAX_SP) { acc += tot[c]; --c; }
        int T = c, A = acc;
        int m = MAX_SP - A; if (m > tot[T]) m = tot[T];   // nu<=512: whole tier
        params[b * 8 + 0] = T;  params[b * 8 + 1] = A;
        params[b * 8 + 2] = m;  params[b * 8 + 3] = nu;
        params[b * 8 + 4] = A + m;                        // nw = min(512, nu)
        sh_T = T;
    }
    __syncthreads();
    int T = sh_T;
    if (tid < NBUK) {
        int ws = 0;
        const int* bh = bhist + ((size_t)b * NBUK + tid) * 256;
        for (int c = T + 1; c < 256; ++c) ws += bh[c];
        wc_[tid] = ws;
        tc_[tid] = bh[T];
    }
    __syncthreads();
    if (tid == 0) {
        int aw = 0, at = 0;
        for (int k = 0; k < NBUK; ++k) {
            wbase[b * NBUK + k] = aw; tbase[b * NBUK + k] = at;
            aw += wc_[k]; at += tc_[k];
        }
    }
}

// ---- K6: cnt16k scan -> winners (any order) + tier (exact id order) ----
__global__ void __launch_bounds__(512) collect2(
    const uint32_t* __restrict__ cnt16k, const int* __restrict__ params,
    const int* __restrict__ wbase, const int* __restrict__ tbase,
    uint32_t* __restrict__ wid, int* __restrict__ wcnt, uint32_t* __restrict__ tier)
{
    int k = blockIdx.x, b = blockIdx.y, tid = threadIdx.x;
    int T = params[b * 8 + 0], m = params[b * 8 + 2];
    int wb = wbase[b * NBUK + k], tb = tbase[b * NBUK + k];
    __shared__ int woff[8];
    __shared__ int wpos;
    if (tid == 0) wpos = 0;
    // per-thread CONTIGUOUS 8 dwords: id order within thread, tid asc
    const u32x4* g = (const u32x4*)(cnt16k + (size_t)(b * NBUK + k) * BUK_DW);
    u32x4 v[2];
    v[0] = g[tid * 2 + 0];
    v[1] = g[tid * 2 + 1];
    __syncthreads();                 // wpos visible
    int base_id = (k * BUK_DW + tid * 8) * 4;
    int ntier = 0;
    #pragma unroll
    for (int q = 0; q < 2; ++q) {
        #pragma unroll
        for (int d = 0; d < 4; ++d) {
            uint32_t w = v[q][d];
            if (!w) continue;
            #pragma unroll
            for (int j = 0; j < 4; ++j) {
                int c = (int)((w >> (j * 8)) & 255u);
                if (c > T) {
                    int p = atomicAdd(&wpos, 1);
                    wid [b * MAX_SP + wb + p] = (uint32_t)(base_id + (q * 4 + d) * 4 + j);
                    wcnt[b * MAX_SP + wb + p] = c;
                } else if (c == T) ++ntier;
            }
        }
    }
    // block exclusive scan of ntier: shfl wave scan + 8-wave offset pass
    int lane = tid & 63, wv = tid >> 6;
    int inc = ntier;
    #pragma unroll
    for (int s = 1; s < 64; s <<= 1) {
        int y = __shfl_up(inc, s);
        if (lane >= s) inc += y;
    }
    if (lane == 63) woff[wv] = inc;
    __syncthreads();
    int pre = inc - ntier;
    for (int i = 0; i < wv; ++i) pre += woff[i];
    if (tb < m && ntier > 0) {           // only blocks that can hold tier[0..m)
        int pos = tb + pre, kk = 0;
        #pragma unroll
        for (int q = 0; q < 2; ++q) {
            #pragma unroll
            for (int d = 0; d < 4; ++d) {
                uint32_t w = v[q][d];
                if (!w) continue;
                #pragma unroll
                for (int j = 0; j < 4; ++j) {
                    int c = (int)((w >> (j * 8)) & 255u);
                    if (c == T) {
                        int q2 = pos + kk; ++kk;
                        if (q2 < TIERCAP) tier[b * TIERCAP + q2] = (uint32_t)(base_id + (q * 4 + d) * 4 + j);
                    }
                }
            }
        }
    }
}

// ---- K7: rank 512 winners; emit PACKED table (idx<<9 | label), sorted by idx ----
__global__ void __launch_bounds__(512) rank512(
    const int* __restrict__ params, const uint32_t* __restrict__ wid,
    const int* __restrict__ wcnt, const uint32_t* __restrict__ tier,
    uint32_t* __restrict__ lookup)
{
    int b = blockIdx.x, tid = threadIdx.x;
    int T = params[b * 8 + 0], A = params[b * 8 + 1];
    int nu = params[b * 8 + 3], nw = params[b * 8 + 4];
    __shared__ uint32_t wu[MAX_SP];
    __shared__ int      wc[MAX_SP];
    if (tid < A)       { wu[tid] = wid[b * MAX_SP + tid]; wc[tid] = wcnt[b * MAX_SP + tid]; }
    else if (tid < nw) { wu[tid] = tier[b * TIERCAP + (tid - A)]; wc[tid] = T; }
    __syncthreads();
    if (tid < nw) {
        uint32_t u = wu[tid]; int c = wc[tid];
        int r = 0, ur = 0;
        for (int j = 0; j < nw; ++j) {
            uint32_t uj = wu[j]; int cj = wc[j];
            r  += ((cj > c) || (cj == c && uj < u)) ? 1 : 0;
            ur += (uj < u) ? 1 : 0;
        }
        int label = (nu <= MAX_SP) ? ur : r;               // inverse branch: id-rank
        lookup[b * MAX_SP + ur] = (u << 9) | (uint32_t)label;   // idx 21b | label 9b
    }
}

// ---- K8: label 4 pts/thread via binary search of packed LDS table ----
__global__ void __launch_bounds__(1024) write_labels4(
    const int* __restrict__ vidx, const int* __restrict__ params,
    const uint32_t* __restrict__ lookup, int* __restrict__ out)
{
    __shared__ uint32_t lu[MAX_SP];
    int b = blockIdx.x >> 6, tid = threadIdx.x;
    if (tid < MAX_SP) lu[tid] = lookup[b * MAX_SP + tid];
    __syncthreads();
    int nw = params[b * 8 + 4];
    size_t p0 = (size_t)b * NPTS + (size_t)(blockIdx.x & 63) * PPB + (size_t)tid * 4;
    i32x4 iv = __builtin_nontemporal_load((const i32x4*)(vidx + p0));
    i32x4 ov;
    #pragma unroll
    for (int j = 0; j < 4; ++j) {
        uint32_t u = (uint32_t)iv[j];
        int lo = 0, hi = nw;
        while (lo < hi) { int mid = (lo + hi) >> 1; if ((lu[mid] >> 9) < u) lo = mid + 1; else hi = mid; }
        int label = 0;
        if (lo < nw && (lu[lo] >> 9) == u) label = (int)(lu[lo] & 511u);
        ov[j] = label;
    }
    __builtin_nontemporal_store(ov, (i32x4*)(out + p0));
}

extern "C" void kernel_launch(void* const* d_in, const int* in_sizes, int n_in,
                              void* d_out, int out_size, void* d_ws, size_t ws_size,
                              hipStream_t stream) {
    const float* coords = (const float*)d_in[0];
    int* out = (int*)d_out;

    uint8_t* p = (uint8_t*)d_ws;
    int*      vidx    = (int*)p;      p += (size_t)BATCHES * NPTS * 4;          // 33.6 MB
    int*      lists   = (int*)p;      p += (size_t)BATCHES * NPTS * 4;          // 33.6 MB
    uint32_t* cnt16k  = (uint32_t*)p; p += (size_t)BATCHES * NBUK * BUK_DW * 4; // 39.8 MB
    int*      blkcnt  = (int*)p;      p += (size_t)BATCHES * BPB * NBUK * 4;    // 623 KB
    int*      blkbase = (int*)p;      p += (size_t)BATCHES * BPB * NBUK * 4;    // 623 KB
    int*      bhist   = (int*)p;      p += (size_t)BATCHES * NBUK * 256 * 4;    // 2.5 MB
    uint32_t* tier    = (uint32_t*)p; p += (size_t)BATCHES * TIERCAP * 4;       // 2.4 MB
    int*      bukbase = (int*)p;      p += (size_t)BATCHES * NBUK * 4;
    int*      buktot  = (int*)p;      p += (size_t)BATCHES * NBUK * 4;
    int*      wbase   = (int*)p;      p += (size_t)BATCHES * NBUK * 4;
    int*      tbase   = (int*)p;      p += (size_t)BATCHES * NBUK * 4;
    int*      params  = (int*)p;      p += (size_t)BATCHES * 8 * 4;
    uint32_t* wid     = (uint32_t*)p; p += (size_t)BATCHES * MAX_SP * 4;
    int*      wcnt    = (int*)p;      p += (size_t)BATCHES * MAX_SP * 4;
    uint32_t* lookup  = (uint32_t*)p; p += (size_t)BATCHES * MAX_SP * 4;

    vidx_count   <<<BATCHES * BPB, 1024, 0, stream>>>(coords, vidx, blkcnt);
    scan64       <<<BATCHES, 128, 0, stream>>>(blkcnt, blkbase, bukbase, buktot);
    scatter4     <<<BATCHES * BPB, 1024, 0, stream>>>(vidx, blkcnt, blkbase, lists);
    bucket_hist  <<<dim3(NBUK, BATCHES), 1024, 0, stream>>>(lists, bukbase, buktot, bhist, cnt16k);
    select_params<<<BATCHES, 256, 0, stream>>>(bhist, params, wbase, tbase);
    collect2     <<<dim3(NBUK, BATCHES), 512, 0, stream>>>(cnt16k, params, wbase, tbase, wid, wcnt, tier);
    rank512      <<<BATCHES, 512, 0, stream>>>(params, wid, wcnt, tier, lookup);
    write_labels4<<<BATCHES * BPB, 1024, 0, stream>>>(vidx, params, lookup, out);
}